// Round 15
// baseline (155.046 us; speedup 1.0000x reference)
//
#include <hip/hip_runtime.h>
#include <math.h>

constexpr int kB = 256;      // batches
constexpr int kT = 261;      // tokens per batch
constexpr int kD = 768;      // dim
constexpr int kC = 5;        // cue tokens
constexpr int kG = 16;       // patch grid
constexpr int kP = 256;      // patches per batch
constexpr int kTok = kT * kD;
constexpr float kTau = 0.03f;   // screening gap threshold (fp32 screen err ~1e-5)
constexpr int kSlots = 64;      // max flagged pairs for parallel recheck

typedef short short8v __attribute__((ext_vector_type(8)));
typedef float f32x4 __attribute__((ext_vector_type(4)));
typedef unsigned short ushort_t;

__device__ inline ushort_t f2bf(float x) {
    unsigned int u = __float_as_uint(x);
    unsigned int r = (u + 0x7FFFu + ((u >> 16) & 1u)) >> 16;
    return (ushort_t)r;
}
__device__ inline float bf2f(ushort_t h) { return __uint_as_float(((unsigned int)h) << 16); }

// ---------------- ws layout (float offsets) ----------------
// sims @0 (327680, aliases tcb; tcb consumed by kmm<1> before ksim2 writes)
// tcb @0 (983040)   u_all @983040   roi @1966080
// bestn(int) @2949120 (1280)
// wsb(ushort) @2951680: Wb_hi, Wb_lo, Wt_hi, Wt_lo (each 589824 ushorts)
// cnt(int) @4131328, flist(int[64]) @4131329
// tcb64g(dbl) @4131400, u64g @4229704, s64g @4328008

// ============ Kprep: split W into bf16 hi/lo, direct + transposed; zero cnt ============
__global__ __launch_bounds__(256)
void kprep(const float* __restrict__ W,
           ushort_t* __restrict__ Wb_hi, ushort_t* __restrict__ Wb_lo,
           ushort_t* __restrict__ Wt_hi, ushort_t* __restrict__ Wt_lo,
           int* __restrict__ cnt)
{
    __shared__ ushort_t Lhi[32][36], Llo[32][36];
    const int blk = blockIdx.x, tr = blk / 24, tc = blk % 24;
    const int t = threadIdx.x, r = t >> 3, q = t & 7;
    if (blk == 0 && t == 0) *cnt = 0;
    const int row = tr * 32 + r, col = tc * 32 + q * 4;
    const float4 v = *(const float4*)&W[(size_t)row * kD + col];
    const ushort_t h0 = f2bf(v.x), h1 = f2bf(v.y), h2 = f2bf(v.z), h3 = f2bf(v.w);
    const ushort_t l0 = f2bf(v.x - bf2f(h0)), l1 = f2bf(v.y - bf2f(h1));
    const ushort_t l2 = f2bf(v.z - bf2f(h2)), l3 = f2bf(v.w - bf2f(h3));
    *(ushort4*)&Wb_hi[(size_t)row * kD + col] = make_ushort4(h0, h1, h2, h3);
    *(ushort4*)&Wb_lo[(size_t)row * kD + col] = make_ushort4(l0, l1, l2, l3);
    Lhi[r][q*4+0] = h0; Lhi[r][q*4+1] = h1; Lhi[r][q*4+2] = h2; Lhi[r][q*4+3] = h3;
    Llo[r][q*4+0] = l0; Llo[r][q*4+1] = l1; Llo[r][q*4+2] = l2; Llo[r][q*4+3] = l3;
    __syncthreads();
    const size_t orow = (size_t)(tc * 32 + r) * kD + tr * 32 + q * 4;
    *(ushort4*)&Wt_hi[orow] = make_ushort4(Lhi[q*4+0][r], Lhi[q*4+1][r], Lhi[q*4+2][r], Lhi[q*4+3][r]);
    *(ushort4*)&Wt_lo[orow] = make_ushort4(Llo[q*4+0][r], Llo[q*4+1][r], Llo[q*4+2][r], Llo[q*4+3][r]);
}

// ============ Kmm: C(1280x768) = A * B via bf16 hi/lo split MFMA (R12, unchanged) ============
template<int MODE>
__global__ __launch_bounds__(256)
void kmm(const float* __restrict__ tokens,
         const ushort_t* __restrict__ Bhi, const ushort_t* __restrict__ Blo,
         const float* __restrict__ bvec, const float* __restrict__ Asrc,
         float* __restrict__ dstA, float* __restrict__ dstB)
{
    __shared__ ushort_t Ah[32][40], Al[32][40];
    __shared__ ushort_t Bh[32][40], Bl[32][40];
    const int mt = blockIdx.x, nt = blockIdx.y, t = threadIdx.x;
    const int w = t >> 6, l = t & 63;
    const int ln = l & 15, kq = l >> 4;
    const int mf = w & 1, nf = w >> 1;
    const int ar = t >> 3, aq = t & 7;
    const int br = t >> 3, bq = t & 7;

    const int am = mt * 32 + ar;
    const float* __restrict__ Ap = (MODE == 0) ? tokens : Asrc;
    const size_t arow = (MODE == 0)
        ? ((size_t)(am / 5) * kTok + (size_t)(am % 5) * kD)
        : ((size_t)am * kD);
    const size_t brow = (size_t)(nt * 32 + br) * kD;

    float4 pa; ushort4 pbh, pbl;
    auto load_regs = [&](int kc) {
        pa  = *(const float4*)&Ap[arow + kc + aq * 4];
        pbh = *(const ushort4*)&Bhi[brow + kc + bq * 4];
        pbl = *(const ushort4*)&Blo[brow + kc + bq * 4];
    };
    auto write_lds = [&]() {
        const ushort_t h0 = f2bf(pa.x), h1 = f2bf(pa.y), h2 = f2bf(pa.z), h3 = f2bf(pa.w);
        const ushort_t a0 = f2bf(pa.x - bf2f(h0)), a1 = f2bf(pa.y - bf2f(h1));
        const ushort_t a2 = f2bf(pa.z - bf2f(h2)), a3 = f2bf(pa.w - bf2f(h3));
        *(ushort4*)&Ah[ar][aq * 4] = make_ushort4(h0, h1, h2, h3);
        *(ushort4*)&Al[ar][aq * 4] = make_ushort4(a0, a1, a2, a3);
        *(ushort4*)&Bh[br][bq * 4] = pbh;
        *(ushort4*)&Bl[br][bq * 4] = pbl;
    };

    f32x4 acc = {0.f, 0.f, 0.f, 0.f};
    auto compute = [&]() {
        const short8v ah  = *(const short8v*)&Ah[mf * 16 + ln][kq * 8];
        const short8v al_ = *(const short8v*)&Al[mf * 16 + ln][kq * 8];
        const short8v bh  = *(const short8v*)&Bh[nf * 16 + ln][kq * 8];
        const short8v bl  = *(const short8v*)&Bl[nf * 16 + ln][kq * 8];
        acc = __builtin_amdgcn_mfma_f32_16x16x32_bf16(al_, bh, acc, 0, 0, 0);
        acc = __builtin_amdgcn_mfma_f32_16x16x32_bf16(ah,  bl, acc, 0, 0, 0);
        acc = __builtin_amdgcn_mfma_f32_16x16x32_bf16(ah,  bh, acc, 0, 0, 0);
    };

    load_regs(0);
    write_lds();
    __syncthreads();
    for (int kc = 32; kc < kD; kc += 32) {
        load_regs(kc);
        compute();
        __syncthreads();
        write_lds();
        __syncthreads();
    }
    compute();

    const int col = nt * 32 + nf * 16 + ln;
    const float bb = (MODE != 1) ? bvec[col] : 0.f;
    #pragma unroll
    for (int r = 0; r < 4; ++r) {
        const int row = mt * 32 + mf * 16 + kq * 4 + r;
        const float val = acc[r] + bb;
        if (MODE == 0) {
            dstA[(size_t)row * kD + col] = val;
            dstB[((size_t)(row / 5) * 10 + (row % 5)) * kD + col] = val;
        } else if (MODE == 1) {
            dstA[(size_t)row * kD + col] = val;
        } else {
            dstA[((size_t)(row / 5) * 10 + 5 + (row % 5)) * kD + col] = val;
        }
    }
}

// ============ Ksim2: fp32 shuffle sims, wave-per-patch, fully coalesced (R4 k3a) ============
__global__ __launch_bounds__(512, 4)
void ksim2(const float* __restrict__ tokens, const float* __restrict__ u_all,
           float* __restrict__ sims)     // [1280][256]
{
    const int blk = blockIdx.x;
    const int b = blk >> 1, half = blk & 1;
    const int t = threadIdx.x;
    const int w = t >> 6, lane = t & 63;
    const size_t tb = (size_t)b * kTok;

    float4 u[kC][3];   // per-lane u fragments (12 floats per cue)
    {
        const float* ub = u_all + (size_t)b * kC * kD + lane * 4;
        #pragma unroll
        for (int c = 0; c < kC; ++c)
            #pragma unroll
            for (int k = 0; k < 3; ++k)
                u[c][k] = *(const float4*)&ub[c * kD + k * 256];
    }
    const int n0 = half * 128 + w * 16;
    for (int i = 0; i < 16; ++i) {
        const int n = n0 + i;
        const float* p = &tokens[tb + (size_t)(kC + n) * kD + lane * 4];
        const float4 p0 = *(const float4*)&p[0];     // wave reads contiguous 1KB
        const float4 p1 = *(const float4*)&p[256];
        const float4 p2 = *(const float4*)&p[512];
        float s[kC];
        #pragma unroll
        for (int c = 0; c < kC; ++c) {
            s[c] = p0.x*u[c][0].x + p0.y*u[c][0].y + p0.z*u[c][0].z + p0.w*u[c][0].w
                 + p1.x*u[c][1].x + p1.y*u[c][1].y + p1.z*u[c][1].z + p1.w*u[c][1].w
                 + p2.x*u[c][2].x + p2.y*u[c][2].y + p2.z*u[c][2].z + p2.w*u[c][2].w;
        }
        #pragma unroll
        for (int off = 32; off >= 1; off >>= 1)
            #pragma unroll
            for (int c = 0; c < kC; ++c)
                s[c] += __shfl_xor(s[c], off, 64);
        float v = s[4];
        if (lane == 0) v = s[0]; else if (lane == 1) v = s[1];
        else if (lane == 2) v = s[2]; else if (lane == 3) v = s[3];
        if (lane < kC)
            sims[((size_t)b * kC + lane) * kP + n] = v;
    }
}

// ============ Kmerge_roi: top-2+flag on sims, ROI for unflagged ============
__global__ __launch_bounds__(768)
void kmerge_roi(const float* __restrict__ sims, const float* __restrict__ tokens,
                int* __restrict__ bestn, int* __restrict__ cnt, int* __restrict__ flist,
                float* __restrict__ roi)
{
    __shared__ int nnS;
    __shared__ int flagS;
    const int pair = blockIdx.x;
    const int t = threadIdx.x;

    if (t < 64) {   // wave 0: top-2 (first-index tie-break)
        const int lane = t;
        const float* s0 = &sims[(size_t)pair * kP];
        float m1 = -3.4e38f, m2 = -3.4e38f; int i1 = 0;
        #pragma unroll
        for (int k = 0; k < 4; ++k) {
            const int n = lane + k * 64;
            const float v = s0[n];
            if (v > m1 || (v == m1 && n < i1)) { m2 = m1; m1 = v; i1 = n; }
            else if (v > m2) m2 = v;
        }
        #pragma unroll
        for (int off = 32; off >= 1; off >>= 1) {
            const float om1 = __shfl_xor(m1, off, 64);
            const int   oi1 = __shfl_xor(i1, off, 64);
            const float om2 = __shfl_xor(m2, off, 64);
            float nm2 = fmaxf(m2, om2);
            if (om1 > m1 || (om1 == m1 && oi1 < i1)) { nm2 = fmaxf(nm2, m1); m1 = om1; i1 = oi1; }
            else nm2 = fmaxf(nm2, om1);
            m2 = nm2;
        }
        if (lane == 0) {
            bestn[pair] = i1;
            nnS = i1;
            const int f = (m1 - m2 < kTau) ? 1 : 0;
            flagS = f;
            if (f) {
                const int i = atomicAdd(cnt, 1);     // device-scope
                if (i < kSlots) flist[i] = pair;
            }
        }
    }
    __syncthreads();
    if (flagS) return;                               // recheck path fixes ROI later

    const int b = pair / 5, c = pair % 5;
    const size_t tb = (size_t)b * kTok;
    const int nn = nnS;
    const int h = nn >> 4, ww = nn & 15;
    const int rlo = max(h - 1, 0), rhi = min(h + 1, kG - 1);
    const int clo = max(ww - 1, 0), chi = min(ww + 1, kG - 1);
    const int d = t;
    float sum = 0.f;
    for (int rr = rlo; rr <= rhi; ++rr)
        for (int cc = clo; cc <= chi; ++cc)
            sum += tokens[tb + (size_t)(kC + rr * kG + cc) * kD + d];
    roi[((size_t)b * kC + c) * kD + d] = sum / (float)((rhi - rlo + 1) * (chi - clo + 1));
}

// ============ Kr_tcb: tcb64[j] for flagged pairs, 12 blocks/pair ============
__global__ __launch_bounds__(256)
void kr_tcb(const float* __restrict__ tokens, const float* __restrict__ W,
            const float* __restrict__ bvec, const int* __restrict__ cnt,
            const int* __restrict__ flist, double* __restrict__ tcb64g)
{
    const int slot = blockIdx.x;
    if (slot >= min(*cnt, kSlots)) return;
    const int pair = flist[slot];
    const int b = pair / 5, c = pair % 5;
    const int js = blockIdx.y;
    const int t = threadIdx.x, w = t >> 6, lane = t & 63;
    const size_t tb = (size_t)b * kTok;

    const float* cuep = &tokens[tb + (size_t)c * kD + lane * 4];
    const float4 cf0 = *(const float4*)&cuep[0];
    const float4 cf1 = *(const float4*)&cuep[256];
    const float4 cf2 = *(const float4*)&cuep[512];
    for (int it = 0; it < 16; ++it) {
        const int j = js * 64 + it * 4 + w;
        const float* wr = &W[(size_t)j * kD + lane * 4];
        const float4 w0 = *(const float4*)&wr[0];
        const float4 w1 = *(const float4*)&wr[256];
        const float4 w2 = *(const float4*)&wr[512];
        double acc = (double)w0.x*cf0.x + (double)w0.y*cf0.y + (double)w0.z*cf0.z + (double)w0.w*cf0.w
                   + (double)w1.x*cf1.x + (double)w1.y*cf1.y + (double)w1.z*cf1.z + (double)w1.w*cf1.w
                   + (double)w2.x*cf2.x + (double)w2.y*cf2.y + (double)w2.z*cf2.z + (double)w2.w*cf2.w;
        #pragma unroll
        for (int off = 32; off >= 1; off >>= 1)
            acc += __shfl_xor(acc, off, 64);
        if (lane == 0) tcb64g[(size_t)slot * kD + j] = acc + (double)bvec[j];
    }
}

// ============ Kr_u: u64[i] = sum_j tcb64[j]*W[j][i], 12 blocks/pair ============
__global__ __launch_bounds__(256)
void kr_u(const float* __restrict__ W, const int* __restrict__ cnt,
          const double* __restrict__ tcb64g, double* __restrict__ u64g)
{
    const int slot = blockIdx.x;
    if (slot >= min(*cnt, kSlots)) return;
    __shared__ double part[4][64];
    const int t = threadIdx.x;
    const int i = t & 63, jq = t >> 6;
    const int i0 = blockIdx.y * 64;

    const double* tc = &tcb64g[(size_t)slot * kD + jq * 192];
    const float* wp = &W[(size_t)(jq * 192) * kD + i0 + i];
    double acc = 0.0;
    #pragma unroll 8
    for (int j = 0; j < 192; ++j)
        acc += tc[j] * (double)wp[(size_t)j * kD];
    part[jq][i] = acc;
    __syncthreads();
    if (t < 64)
        u64g[(size_t)slot * kD + i0 + t] = part[0][t] + part[1][t] + part[2][t] + part[3][t];
}

// ============ Kr_sim: fp64 sims for flagged pairs, 8 blocks/pair ============
__global__ __launch_bounds__(256)
void kr_sim(const float* __restrict__ tokens, const int* __restrict__ cnt,
            const int* __restrict__ flist, const double* __restrict__ u64g,
            double* __restrict__ s64g)
{
    const int slot = blockIdx.x;
    if (slot >= min(*cnt, kSlots)) return;
    __shared__ double u64s[kD];
    const int pair = flist[slot];
    const int b = pair / 5;
    const int ps = blockIdx.y;
    const int t = threadIdx.x, w = t >> 6, lane = t & 63;
    const size_t tb = (size_t)b * kTok;

    u64s[t]       = u64g[(size_t)slot * kD + t];
    u64s[t + 256] = u64g[(size_t)slot * kD + t + 256];
    u64s[t + 512] = u64g[(size_t)slot * kD + t + 512];
    __syncthreads();

    #pragma unroll
    for (int it = 0; it < 8; ++it) {
        const int n = ps * 32 + w * 8 + it;
        const float* p = &tokens[tb + (size_t)(kC + n) * kD + lane * 4];
        const float4 p0 = *(const float4*)&p[0];
        const float4 p1 = *(const float4*)&p[256];
        const float4 p2 = *(const float4*)&p[512];
        const double* ud = &u64s[lane * 4];
        double acc = (double)p0.x*ud[0]   + (double)p0.y*ud[1]   + (double)p0.z*ud[2]   + (double)p0.w*ud[3]
                   + (double)p1.x*ud[256] + (double)p1.y*ud[257] + (double)p1.z*ud[258] + (double)p1.w*ud[259]
                   + (double)p2.x*ud[512] + (double)p2.y*ud[513] + (double)p2.z*ud[514] + (double)p2.w*ud[515];
        #pragma unroll
        for (int off = 32; off >= 1; off >>= 1)
            acc += __shfl_xor(acc, off, 64);
        if (lane == 0) s64g[(size_t)slot * kP + n] = acc;
    }
}

// ============ Kr_argroi: fp64 argmax + ROI for flagged pairs ============
__global__ __launch_bounds__(768)
void kr_argroi(const float* __restrict__ tokens, const int* __restrict__ cnt,
               const int* __restrict__ flist, const double* __restrict__ s64g,
               int* __restrict__ bestn, float* __restrict__ roi)
{
    const int slot = blockIdx.x;
    if (slot >= min(*cnt, kSlots)) return;
    __shared__ int nnS;
    const int t = threadIdx.x;
    if (t < 64) {
        const int lane = t;
        const double* s = &s64g[(size_t)slot * kP];
        double best = -1.0e300; int bi = 0;
        #pragma unroll
        for (int k = 0; k < 4; ++k) {
            const int n = lane + k * 64;
            const double v = s[n];
            if (v > best || (v == best && n < bi)) { best = v; bi = n; }
        }
        #pragma unroll
        for (int off = 32; off >= 1; off >>= 1) {
            const double v2 = __shfl_xor(best, off, 64);
            const int    i2 = __shfl_xor(bi, off, 64);
            if (v2 > best || (v2 == best && i2 < bi)) { best = v2; bi = i2; }
        }
        if (lane == 0) { bestn[flist[slot]] = bi; nnS = bi; }
    }
    __syncthreads();
    const int pair = flist[slot];
    const int b = pair / 5, c = pair % 5;
    const size_t tb = (size_t)b * kTok;
    const int nn = nnS;
    const int h = nn >> 4, ww = nn & 15;
    const int rlo = max(h - 1, 0), rhi = min(h + 1, kG - 1);
    const int clo = max(ww - 1, 0), chi = min(ww + 1, kG - 1);
    const int d = t;
    float sum = 0.f;
    for (int rr = rlo; rr <= rhi; ++rr)
        for (int cc = clo; cc <= chi; ++cc)
            sum += tokens[tb + (size_t)(kC + rr * kG + cc) * kD + d];
    roi[((size_t)b * kC + c) * kD + d] = sum / (float)((rhi - rlo + 1) * (chi - clo + 1));
}

// ============ Knorm: row-wise L2 normalize (in-place on out) ============
__global__ __launch_bounds__(256)
void knorm(float* __restrict__ out)
{
    __shared__ float wsum[4];
    const int row = blockIdx.x, t = threadIdx.x;
    float* p = out + (size_t)row * kD;
    const float x0 = p[t], x1 = p[t + 256], x2 = p[t + 512];
    float ss = x0 * x0 + x1 * x1 + x2 * x2;
    #pragma unroll
    for (int off = 32; off >= 1; off >>= 1) ss += __shfl_down(ss, off, 64);
    if ((t & 63) == 0) wsum[t >> 6] = ss;
    __syncthreads();
    const float tot = wsum[0] + wsum[1] + wsum[2] + wsum[3];
    const float nrm = fmaxf(sqrtf(tot), 1e-12f);
    p[t] = x0 / nrm; p[t + 256] = x1 / nrm; p[t + 512] = x2 / nrm;
}

extern "C" void kernel_launch(void* const* d_in, const int* in_sizes, int n_in,
                              void* d_out, int out_size, void* d_ws, size_t ws_size,
                              hipStream_t stream) {
    const float* tokens = (const float*)d_in[0];
    const float* W      = (const float*)d_in[1];
    const float* bvec   = (const float*)d_in[2];
    float* out = (float*)d_out;
    float* ws = (float*)d_ws;
    float* sims  = ws;                 // aliases tcb (tcb dead before ksim2 writes)
    float* tcb   = ws;
    float* u_all = ws + 983040;
    float* roi   = ws + 1966080;
    int*   bestn = (int*)(ws + 2949120);
    ushort_t* wsb = (ushort_t*)(ws + 2951680);
    ushort_t* Wb_hi = wsb;
    ushort_t* Wb_lo = wsb + 589824;
    ushort_t* Wt_hi = wsb + 1179648;
    ushort_t* Wt_lo = wsb + 1769472;
    int*    cnt    = (int*)(ws + 4131328);
    int*    flist  = (int*)(ws + 4131329);
    double* tcb64g = (double*)(ws + 4131400);
    double* u64g   = (double*)(ws + 4229704);
    double* s64g   = (double*)(ws + 4328008);

    kprep<<<dim3(576), 256, 0, stream>>>(W, Wb_hi, Wb_lo, Wt_hi, Wt_lo, cnt);
    kmm<0><<<dim3(40, 24), 256, 0, stream>>>(tokens, Wb_hi, Wb_lo, bvec, nullptr, tcb, out);
    kmm<1><<<dim3(40, 24), 256, 0, stream>>>(tokens, Wt_hi, Wt_lo, bvec, tcb, u_all, nullptr);
    ksim2<<<dim3(512), 512, 0, stream>>>(tokens, u_all, sims);
    kmerge_roi<<<dim3(1280), 768, 0, stream>>>(sims, tokens, bestn, cnt, flist, roi);
    kr_tcb<<<dim3(kSlots, 12), 256, 0, stream>>>(tokens, W, bvec, cnt, flist, tcb64g);
    kr_u<<<dim3(kSlots, 12), 256, 0, stream>>>(W, cnt, tcb64g, u64g);
    kr_sim<<<dim3(kSlots, 8), 256, 0, stream>>>(tokens, cnt, flist, u64g, s64g);
    kr_argroi<<<dim3(kSlots), 768, 0, stream>>>(tokens, cnt, flist, s64g, bestn, roi);
    kmm<2><<<dim3(40, 24), 256, 0, stream>>>(tokens, Wb_hi, Wb_lo, bvec, roi, out, nullptr);
    knorm<<<dim3(2560), 256, 0, stream>>>(out);
}

// Round 16
// 149.654 us; speedup vs baseline: 1.0360x; 1.0360x over previous
//
#include <hip/hip_runtime.h>
#include <math.h>

constexpr int kB = 256;      // batches
constexpr int kT = 261;      // tokens per batch
constexpr int kD = 768;      // dim
constexpr int kC = 5;        // cue tokens
constexpr int kG = 16;       // patch grid
constexpr int kP = 256;      // patches per batch
constexpr int kTok = kT * kD;
constexpr float kTau = 0.03f;   // screening gap threshold
constexpr int kSlots = 64;      // max flagged pairs for parallel recheck

typedef short short8v __attribute__((ext_vector_type(8)));
typedef float f32x4 __attribute__((ext_vector_type(4)));
typedef unsigned short ushort_t;

__device__ inline ushort_t f2bf(float x) {
    unsigned int u = __float_as_uint(x);
    unsigned int r = (u + 0x7FFFu + ((u >> 16) & 1u)) >> 16;
    return (ushort_t)r;
}
__device__ inline float bf2f(ushort_t h) { return __uint_as_float(((unsigned int)h) << 16); }

// ---------------- ws layout (float offsets) ----------------
// tcb @0 (983040)   u_all @983040   roi @1966080
// bestn(int) @2949120 (1280)
// wsb(ushort) @2951680: Wb_hi, Wb_lo, Wt_hi, Wt_lo (each 589824 ushorts)
// cnt(int) @4131328, flist(int[64]) @4131329
// tcb64g(dbl) @4131400, u64g @4229704, s64g @4328008

// ============ Kprep: split W into bf16 hi/lo, direct + transposed; zero cnt ============
__global__ __launch_bounds__(256)
void kprep(const float* __restrict__ W,
           ushort_t* __restrict__ Wb_hi, ushort_t* __restrict__ Wb_lo,
           ushort_t* __restrict__ Wt_hi, ushort_t* __restrict__ Wt_lo,
           int* __restrict__ cnt)
{
    __shared__ ushort_t Lhi[32][36], Llo[32][36];
    const int blk = blockIdx.x, tr = blk / 24, tc = blk % 24;
    const int t = threadIdx.x, r = t >> 3, q = t & 7;
    if (blk == 0 && t == 0) *cnt = 0;
    const int row = tr * 32 + r, col = tc * 32 + q * 4;
    const float4 v = *(const float4*)&W[(size_t)row * kD + col];
    const ushort_t h0 = f2bf(v.x), h1 = f2bf(v.y), h2 = f2bf(v.z), h3 = f2bf(v.w);
    const ushort_t l0 = f2bf(v.x - bf2f(h0)), l1 = f2bf(v.y - bf2f(h1));
    const ushort_t l2 = f2bf(v.z - bf2f(h2)), l3 = f2bf(v.w - bf2f(h3));
    *(ushort4*)&Wb_hi[(size_t)row * kD + col] = make_ushort4(h0, h1, h2, h3);
    *(ushort4*)&Wb_lo[(size_t)row * kD + col] = make_ushort4(l0, l1, l2, l3);
    Lhi[r][q*4+0] = h0; Lhi[r][q*4+1] = h1; Lhi[r][q*4+2] = h2; Lhi[r][q*4+3] = h3;
    Llo[r][q*4+0] = l0; Llo[r][q*4+1] = l1; Llo[r][q*4+2] = l2; Llo[r][q*4+3] = l3;
    __syncthreads();
    const size_t orow = (size_t)(tc * 32 + r) * kD + tr * 32 + q * 4;
    *(ushort4*)&Wt_hi[orow] = make_ushort4(Lhi[q*4+0][r], Lhi[q*4+1][r], Lhi[q*4+2][r], Lhi[q*4+3][r]);
    *(ushort4*)&Wt_lo[orow] = make_ushort4(Llo[q*4+0][r], Llo[q*4+1][r], Llo[q*4+2][r], Llo[q*4+3][r]);
}

// ============ Kmm: C(1280x768) = A * B via bf16 hi/lo split MFMA ============
template<int MODE>
__global__ __launch_bounds__(256)
void kmm(const float* __restrict__ tokens,
         const ushort_t* __restrict__ Bhi, const ushort_t* __restrict__ Blo,
         const float* __restrict__ bvec, const float* __restrict__ Asrc,
         float* __restrict__ dstA, float* __restrict__ dstB)
{
    __shared__ ushort_t Ah[32][40], Al[32][40];
    __shared__ ushort_t Bh[32][40], Bl[32][40];
    const int mt = blockIdx.x, nt = blockIdx.y, t = threadIdx.x;
    const int w = t >> 6, l = t & 63;
    const int ln = l & 15, kq = l >> 4;
    const int mf = w & 1, nf = w >> 1;
    const int ar = t >> 3, aq = t & 7;
    const int br = t >> 3, bq = t & 7;

    const int am = mt * 32 + ar;
    const float* __restrict__ Ap = (MODE == 0) ? tokens : Asrc;
    const size_t arow = (MODE == 0)
        ? ((size_t)(am / 5) * kTok + (size_t)(am % 5) * kD)
        : ((size_t)am * kD);
    const size_t brow = (size_t)(nt * 32 + br) * kD;

    float4 pa; ushort4 pbh, pbl;
    auto load_regs = [&](int kc) {
        pa  = *(const float4*)&Ap[arow + kc + aq * 4];
        pbh = *(const ushort4*)&Bhi[brow + kc + bq * 4];
        pbl = *(const ushort4*)&Blo[brow + kc + bq * 4];
    };
    auto write_lds = [&]() {
        const ushort_t h0 = f2bf(pa.x), h1 = f2bf(pa.y), h2 = f2bf(pa.z), h3 = f2bf(pa.w);
        const ushort_t a0 = f2bf(pa.x - bf2f(h0)), a1 = f2bf(pa.y - bf2f(h1));
        const ushort_t a2 = f2bf(pa.z - bf2f(h2)), a3 = f2bf(pa.w - bf2f(h3));
        *(ushort4*)&Ah[ar][aq * 4] = make_ushort4(h0, h1, h2, h3);
        *(ushort4*)&Al[ar][aq * 4] = make_ushort4(a0, a1, a2, a3);
        *(ushort4*)&Bh[br][bq * 4] = pbh;
        *(ushort4*)&Bl[br][bq * 4] = pbl;
    };

    f32x4 acc = {0.f, 0.f, 0.f, 0.f};
    auto compute = [&]() {
        const short8v ah  = *(const short8v*)&Ah[mf * 16 + ln][kq * 8];
        const short8v al_ = *(const short8v*)&Al[mf * 16 + ln][kq * 8];
        const short8v bh  = *(const short8v*)&Bh[nf * 16 + ln][kq * 8];
        const short8v bl  = *(const short8v*)&Bl[nf * 16 + ln][kq * 8];
        acc = __builtin_amdgcn_mfma_f32_16x16x32_bf16(al_, bh, acc, 0, 0, 0);
        acc = __builtin_amdgcn_mfma_f32_16x16x32_bf16(ah,  bl, acc, 0, 0, 0);
        acc = __builtin_amdgcn_mfma_f32_16x16x32_bf16(ah,  bh, acc, 0, 0, 0);
    };

    load_regs(0);
    write_lds();
    __syncthreads();
    for (int kc = 32; kc < kD; kc += 32) {
        load_regs(kc);
        compute();
        __syncthreads();
        write_lds();
        __syncthreads();
    }
    compute();

    const int col = nt * 32 + nf * 16 + ln;
    const float bb = (MODE != 1) ? bvec[col] : 0.f;
    #pragma unroll
    for (int r = 0; r < 4; ++r) {
        const int row = mt * 32 + mf * 16 + kq * 4 + r;
        const float val = acc[r] + bb;
        if (MODE == 0) {
            dstA[(size_t)row * kD + col] = val;
            dstB[((size_t)(row / 5) * 10 + (row % 5)) * kD + col] = val;
        } else if (MODE == 1) {
            dstA[(size_t)row * kD + col] = val;
        } else {
            dstA[((size_t)(row / 5) * 10 + 5 + (row % 5)) * kD + col] = val;
        }
    }
}

// ============ Ksim_fused: streaming MFMA sims + top-2/flag + ROI(unflagged) ============
// 1 block per batch, 1024 threads (16 waves x 16 patches), full K per patch.
__global__ __launch_bounds__(1024, 1)
void ksim_fused(const float* __restrict__ tokens, const float* __restrict__ u_all,
                int* __restrict__ bestn, int* __restrict__ cnt, int* __restrict__ flist,
                float* __restrict__ roi)
{
    __shared__ ushort_t Uh[6][776], Ul[6][776];
    __shared__ float simsL[kC][kP];
    __shared__ int bestnL[kC];
    __shared__ int flagL;
    const int b = blockIdx.x, t = threadIdx.x;
    const int w = t >> 6, lane = t & 63;
    const int ln = lane & 15, kq = lane >> 4;
    const size_t tb = (size_t)b * kTok;
    if (t == 0) flagL = 0;

    // ---- u -> bf16 hi/lo LDS (row 5 = zeros) ----
    if (t < kD) {
        const float* ub = u_all + (size_t)b * kC * kD;
        #pragma unroll
        for (int c = 0; c < kC; ++c) {
            const float v = ub[(size_t)c * kD + t];
            const ushort_t h = f2bf(v);
            Uh[c][t] = h; Ul[c][t] = f2bf(v - bf2f(h));
        }
    }
    if (t < 776) { Uh[kC][t] = 0; Ul[kC][t] = 0; }
    __syncthreads();

    // ---- streaming sims, full K, wave w -> patches w*16..+15 ----
    const int urow = (ln < kC) ? ln : kC;
    const int n0 = w * 16;
    const float* __restrict__ prow = &tokens[tb + (size_t)(kC + n0 + ln) * kD + kq * 8];
    f32x4 acc = {0.f, 0.f, 0.f, 0.f};
    #pragma unroll
    for (int c = 0; c < 24; ++c) {
        const float4 fa = *(const float4*)&prow[c * 32];
        const float4 fb = *(const float4*)&prow[c * 32 + 4];
        const float fv[8] = {fa.x, fa.y, fa.z, fa.w, fb.x, fb.y, fb.z, fb.w};
        short8v bh, bl;
        #pragma unroll
        for (int j = 0; j < 8; ++j) {
            const ushort_t h = f2bf(fv[j]);
            bh[j] = (short)h;
            bl[j] = (short)f2bf(fv[j] - bf2f(h));
        }
        const short8v ah  = *(const short8v*)&Uh[urow][c * 32 + kq * 8];
        const short8v al_ = *(const short8v*)&Ul[urow][c * 32 + kq * 8];
        acc = __builtin_amdgcn_mfma_f32_16x16x32_bf16(al_, bh, acc, 0, 0, 0);
        acc = __builtin_amdgcn_mfma_f32_16x16x32_bf16(ah,  bl, acc, 0, 0, 0);
        acc = __builtin_amdgcn_mfma_f32_16x16x32_bf16(ah,  bh, acc, 0, 0, 0);
    }
    // D layout: row(c) = kq*4 + r, col = ln
    if (kq == 0) {
        #pragma unroll
        for (int r = 0; r < 4; ++r) simsL[r][n0 + ln] = acc[r];
    } else if (kq == 1) {
        simsL[4][n0 + ln] = acc[0];
    }
    __syncthreads();

    // ---- top-2 per cue (waves 0..4), flag append ----
    if (w < kC) {
        const int c = w;
        float m1 = -3.4e38f, m2 = -3.4e38f; int i1 = 0;
        #pragma unroll
        for (int k = 0; k < 4; ++k) {
            const int n = lane + k * 64;
            const float v = simsL[c][n];
            if (v > m1 || (v == m1 && n < i1)) { m2 = m1; m1 = v; i1 = n; }
            else if (v > m2) m2 = v;
        }
        #pragma unroll
        for (int off = 32; off >= 1; off >>= 1) {
            const float om1 = __shfl_xor(m1, off, 64);
            const int   oi1 = __shfl_xor(i1, off, 64);
            const float om2 = __shfl_xor(m2, off, 64);
            float nm2 = fmaxf(m2, om2);
            if (om1 > m1 || (om1 == m1 && oi1 < i1)) { nm2 = fmaxf(nm2, m1); m1 = om1; i1 = oi1; }
            else nm2 = fmaxf(nm2, om1);
            m2 = nm2;
        }
        if (lane == 0) {
            bestnL[c] = i1;
            bestn[b * kC + c] = i1;
            if (m1 - m2 < kTau) {
                atomicOr(&flagL, 1 << c);
                const int i = atomicAdd(cnt, 1);     // device-scope
                if (i < kSlots) flist[i] = b * kC + c;
            }
        }
    }
    __syncthreads();

    // ---- ROI means for unflagged cues (t < 768, one d each) ----
    if (t < kD) {
        const int d = t;
        #pragma unroll
        for (int c = 0; c < kC; ++c) {
            if (flagL & (1 << c)) continue;
            const int nn = bestnL[c];
            const int h = nn >> 4, ww = nn & 15;
            const int rlo = max(h - 1, 0), rhi = min(h + 1, kG - 1);
            const int clo = max(ww - 1, 0), chi = min(ww + 1, kG - 1);
            float sum = 0.f;
            for (int rr = rlo; rr <= rhi; ++rr)
                for (int cc = clo; cc <= chi; ++cc)
                    sum += tokens[tb + (size_t)(kC + rr * kG + cc) * kD + d];
            roi[((size_t)b * kC + c) * kD + d] = sum / (float)((rhi - rlo + 1) * (chi - clo + 1));
        }
    }
}

// ============ Kr_tcb: tcb64[j] for flagged pairs, 12 blocks/pair ============
__global__ __launch_bounds__(256)
void kr_tcb(const float* __restrict__ tokens, const float* __restrict__ W,
            const float* __restrict__ bvec, const int* __restrict__ cnt,
            const int* __restrict__ flist, double* __restrict__ tcb64g)
{
    const int slot = blockIdx.x;
    if (slot >= min(*cnt, kSlots)) return;
    const int pair = flist[slot];
    const int b = pair / 5, c = pair % 5;
    const int js = blockIdx.y;
    const int t = threadIdx.x, w = t >> 6, lane = t & 63;
    const size_t tb = (size_t)b * kTok;

    const float* cuep = &tokens[tb + (size_t)c * kD + lane * 4];
    const float4 cf0 = *(const float4*)&cuep[0];
    const float4 cf1 = *(const float4*)&cuep[256];
    const float4 cf2 = *(const float4*)&cuep[512];
    for (int it = 0; it < 16; ++it) {
        const int j = js * 64 + it * 4 + w;
        const float* wr = &W[(size_t)j * kD + lane * 4];
        const float4 w0 = *(const float4*)&wr[0];
        const float4 w1 = *(const float4*)&wr[256];
        const float4 w2 = *(const float4*)&wr[512];
        double acc = (double)w0.x*cf0.x + (double)w0.y*cf0.y + (double)w0.z*cf0.z + (double)w0.w*cf0.w
                   + (double)w1.x*cf1.x + (double)w1.y*cf1.y + (double)w1.z*cf1.z + (double)w1.w*cf1.w
                   + (double)w2.x*cf2.x + (double)w2.y*cf2.y + (double)w2.z*cf2.z + (double)w2.w*cf2.w;
        #pragma unroll
        for (int off = 32; off >= 1; off >>= 1)
            acc += __shfl_xor(acc, off, 64);
        if (lane == 0) tcb64g[(size_t)slot * kD + j] = acc + (double)bvec[j];
    }
}

// ============ Kr_u: u64[i] = sum_j tcb64[j]*W[j][i], 12 blocks/pair ============
__global__ __launch_bounds__(256)
void kr_u(const float* __restrict__ W, const int* __restrict__ cnt,
          const double* __restrict__ tcb64g, double* __restrict__ u64g)
{
    const int slot = blockIdx.x;
    if (slot >= min(*cnt, kSlots)) return;
    __shared__ double part[4][64];
    const int t = threadIdx.x;
    const int i = t & 63, jq = t >> 6;
    const int i0 = blockIdx.y * 64;

    const double* tc = &tcb64g[(size_t)slot * kD + jq * 192];
    const float* wp = &W[(size_t)(jq * 192) * kD + i0 + i];
    double acc = 0.0;
    #pragma unroll 8
    for (int j = 0; j < 192; ++j)
        acc += tc[j] * (double)wp[(size_t)j * kD];
    part[jq][i] = acc;
    __syncthreads();
    if (t < 64)
        u64g[(size_t)slot * kD + i0 + t] = part[0][t] + part[1][t] + part[2][t] + part[3][t];
}

// ============ Kr_sim: fp64 sims for flagged pairs, 8 blocks/pair ============
__global__ __launch_bounds__(256)
void kr_sim(const float* __restrict__ tokens, const int* __restrict__ cnt,
            const int* __restrict__ flist, const double* __restrict__ u64g,
            double* __restrict__ s64g)
{
    const int slot = blockIdx.x;
    if (slot >= min(*cnt, kSlots)) return;
    __shared__ double u64s[kD];
    const int pair = flist[slot];
    const int b = pair / 5;
    const int ps = blockIdx.y;
    const int t = threadIdx.x, w = t >> 6, lane = t & 63;
    const size_t tb = (size_t)b * kTok;

    u64s[t]       = u64g[(size_t)slot * kD + t];
    u64s[t + 256] = u64g[(size_t)slot * kD + t + 256];
    u64s[t + 512] = u64g[(size_t)slot * kD + t + 512];
    __syncthreads();

    #pragma unroll
    for (int it = 0; it < 8; ++it) {
        const int n = ps * 32 + w * 8 + it;
        const float* p = &tokens[tb + (size_t)(kC + n) * kD + lane * 4];
        const float4 p0 = *(const float4*)&p[0];
        const float4 p1 = *(const float4*)&p[256];
        const float4 p2 = *(const float4*)&p[512];
        const double* ud = &u64s[lane * 4];
        double acc = (double)p0.x*ud[0]   + (double)p0.y*ud[1]   + (double)p0.z*ud[2]   + (double)p0.w*ud[3]
                   + (double)p1.x*ud[256] + (double)p1.y*ud[257] + (double)p1.z*ud[258] + (double)p1.w*ud[259]
                   + (double)p2.x*ud[512] + (double)p2.y*ud[513] + (double)p2.z*ud[514] + (double)p2.w*ud[515];
        #pragma unroll
        for (int off = 32; off >= 1; off >>= 1)
            acc += __shfl_xor(acc, off, 64);
        if (lane == 0) s64g[(size_t)slot * kP + n] = acc;
    }
}

// ============ Kr_arg: fp64 argmax per flagged pair ============
__global__ __launch_bounds__(64)
void kr_arg(const int* __restrict__ cnt, const int* __restrict__ flist,
            const double* __restrict__ s64g, int* __restrict__ bestn)
{
    const int slot = blockIdx.x;
    if (slot >= min(*cnt, kSlots)) return;
    const int lane = threadIdx.x;
    const double* s = &s64g[(size_t)slot * kP];
    double best = -1.0e300; int bi = 0;
    #pragma unroll
    for (int k = 0; k < 4; ++k) {
        const int n = lane + k * 64;
        const double v = s[n];
        if (v > best || (v == best && n < bi)) { best = v; bi = n; }
    }
    #pragma unroll
    for (int off = 32; off >= 1; off >>= 1) {
        const double v2 = __shfl_xor(best, off, 64);
        const int    i2 = __shfl_xor(bi, off, 64);
        if (v2 > best || (v2 == best && i2 < bi)) { best = v2; bi = i2; }
    }
    if (lane == 0) bestn[flist[slot]] = bi;
}

// ============ Kroi_fix: ROI means for flagged pairs only ============
__global__ __launch_bounds__(768)
void kroi_fix(const float* __restrict__ tokens, const int* __restrict__ cnt,
              const int* __restrict__ flist, const int* __restrict__ bestn,
              float* __restrict__ roi)
{
    const int slot = blockIdx.x;
    if (slot >= min(*cnt, kSlots)) return;
    const int pair = flist[slot];
    const int b = pair / 5, c = pair % 5;
    const int d = threadIdx.x;
    const size_t tb = (size_t)b * kTok;
    const int nn = bestn[pair];
    const int h = nn >> 4, ww = nn & 15;
    const int rlo = max(h - 1, 0), rhi = min(h + 1, kG - 1);
    const int clo = max(ww - 1, 0), chi = min(ww + 1, kG - 1);
    float sum = 0.f;
    for (int rr = rlo; rr <= rhi; ++rr)
        for (int cc = clo; cc <= chi; ++cc)
            sum += tokens[tb + (size_t)(kC + rr * kG + cc) * kD + d];
    roi[((size_t)b * kC + c) * kD + d] = sum / (float)((rhi - rlo + 1) * (chi - clo + 1));
}

// ============ Knorm: row-wise L2 normalize (in-place on out) ============
__global__ __launch_bounds__(256)
void knorm(float* __restrict__ out)
{
    __shared__ float wsum[4];
    const int row = blockIdx.x, t = threadIdx.x;
    float* p = out + (size_t)row * kD;
    const float x0 = p[t], x1 = p[t + 256], x2 = p[t + 512];
    float ss = x0 * x0 + x1 * x1 + x2 * x2;
    #pragma unroll
    for (int off = 32; off >= 1; off >>= 1) ss += __shfl_down(ss, off, 64);
    if ((t & 63) == 0) wsum[t >> 6] = ss;
    __syncthreads();
    const float tot = wsum[0] + wsum[1] + wsum[2] + wsum[3];
    const float nrm = fmaxf(sqrtf(tot), 1e-12f);
    p[t] = x0 / nrm; p[t + 256] = x1 / nrm; p[t + 512] = x2 / nrm;
}

extern "C" void kernel_launch(void* const* d_in, const int* in_sizes, int n_in,
                              void* d_out, int out_size, void* d_ws, size_t ws_size,
                              hipStream_t stream) {
    const float* tokens = (const float*)d_in[0];
    const float* W      = (const float*)d_in[1];
    const float* bvec   = (const float*)d_in[2];
    float* out = (float*)d_out;
    float* ws = (float*)d_ws;
    float* tcb   = ws;
    float* u_all = ws + 983040;
    float* roi   = ws + 1966080;
    int*   bestn = (int*)(ws + 2949120);
    ushort_t* wsb = (ushort_t*)(ws + 2951680);
    ushort_t* Wb_hi = wsb;
    ushort_t* Wb_lo = wsb + 589824;
    ushort_t* Wt_hi = wsb + 1179648;
    ushort_t* Wt_lo = wsb + 1769472;
    int*    cnt    = (int*)(ws + 4131328);
    int*    flist  = (int*)(ws + 4131329);
    double* tcb64g = (double*)(ws + 4131400);
    double* u64g   = (double*)(ws + 4229704);
    double* s64g   = (double*)(ws + 4328008);

    kprep<<<dim3(576), 256, 0, stream>>>(W, Wb_hi, Wb_lo, Wt_hi, Wt_lo, cnt);
    kmm<0><<<dim3(40, 24), 256, 0, stream>>>(tokens, Wb_hi, Wb_lo, bvec, nullptr, tcb, out);
    kmm<1><<<dim3(40, 24), 256, 0, stream>>>(tokens, Wt_hi, Wt_lo, bvec, tcb, u_all, nullptr);
    ksim_fused<<<dim3(256), 1024, 0, stream>>>(tokens, u_all, bestn, cnt, flist, roi);
    kr_tcb<<<dim3(kSlots, 12), 256, 0, stream>>>(tokens, W, bvec, cnt, flist, tcb64g);
    kr_u<<<dim3(kSlots, 12), 256, 0, stream>>>(W, cnt, tcb64g, u64g);
    kr_sim<<<dim3(kSlots, 8), 256, 0, stream>>>(tokens, cnt, flist, u64g, s64g);
    kr_arg<<<dim3(kSlots), 64, 0, stream>>>(cnt, flist, s64g, bestn);
    kroi_fix<<<dim3(kSlots), 768, 0, stream>>>(tokens, cnt, flist, bestn, roi);
    kmm<2><<<dim3(40, 24), 256, 0, stream>>>(tokens, Wb_hi, Wb_lo, bvec, roi, out, nullptr);
    knorm<<<dim3(2560), 256, 0, stream>>>(out);
}